// Round 4
// baseline (454.425 us; speedup 1.0000x reference)
//
#include <hip/hip_runtime.h>
#include <hip/hip_bf16.h>

// Problem constants
#define BB 32
#define CIN 96
#define TT 288
#define VV 25
#define SS 3
#define COUT 96
#define WSZ 5
#define BN_EPS 1e-5f
#define TV (TT*VV)              // 7200
#define ELEMS (BB*COUT*TV)      // 22118400
#define MK 2400                 // GEMM K = (i,n)
#define GMP 2432                // GEMM M padded (19 x 128), true M = 2400 = (c,m)
#define GN 9216                 // GEMM N = (b,t)

typedef __attribute__((ext_vector_type(8))) short bf16x8;
typedef __attribute__((ext_vector_type(4))) float f32x4;

__device__ __forceinline__ void gload_lds16(const void* g, void* l) {
    __builtin_amdgcn_global_load_lds(
        (const __attribute__((address_space(1))) unsigned int*)g,
        (__attribute__((address_space(3))) unsigned int*)l, 16, 0, 0);
}

__device__ __forceinline__ unsigned short f2bf(float f) {
    unsigned u = __float_as_uint(f);
    return (unsigned short)((u + 0x7fffu + ((u >> 16) & 1u)) >> 16);  // RNE
}

// ---------------------------------------------------------------------------
// wprep: W2b[row=(c,mv)][kk=(i,n)] = sum_s w[s*96+c, i] * A[s, n, mv]  (bf16)
// rows 2400..2431 zero-padded. Also computes zbias[row] and zeroes ssum/ssq.
// ---------------------------------------------------------------------------
__global__ __launch_bounds__(256) void wprep(const float* __restrict__ w,
                                             const float* __restrict__ A,
                                             const float* __restrict__ cb,
                                             __hip_bfloat16* __restrict__ W2b,
                                             float* __restrict__ zbias,
                                             float* __restrict__ stats /*192 floats*/)
{
    __shared__ float Ash[SS*VV*VV];   // 1875 floats
    __shared__ float wsh[SS*CIN];     // 288 floats
    const int tid = threadIdx.x;
    const int row = blockIdx.x;
    __hip_bfloat16* orow = W2b + (size_t)row * MK;
    if (row == 0 && tid < 2*COUT) stats[tid] = 0.0f;
    if (row >= 2400) {
        for (int kk = tid; kk < MK; kk += 256) orow[kk] = __float2bfloat16(0.0f);
        return;
    }
    const int c = row / VV, mv = row - c*VV;
    for (int e = tid; e < SS*VV*VV; e += 256) Ash[e] = A[e];
    for (int e = tid; e < SS*CIN; e += 256) {
        int s = e / CIN, i = e - s*CIN;
        wsh[e] = w[(s*COUT + c)*CIN + i];
    }
    __syncthreads();
    for (int kk = tid; kk < MK; kk += 256) {
        int i = kk / VV, n = kk - i*VV;
        float v = 0.f;
        #pragma unroll
        for (int s = 0; s < SS; ++s)
            v = fmaf(wsh[s*CIN + i], Ash[(s*VV + n)*VV + mv], v);
        orow[kk] = __float2bfloat16(v);
    }
    if (tid == 0) {
        float v = 0.f;
        #pragma unroll
        for (int s = 0; s < SS; ++s) {
            float sa = 0.f;
            #pragma unroll
            for (int n = 0; n < VV; ++n) sa += Ash[(s*VV + n)*VV + mv];
            v = fmaf(cb[s*COUT + c], sa, v);
        }
        zbias[row] = v;
    }
}

// ---------------------------------------------------------------------------
// xprep_t: LDS-tiled transpose x[b][i][t][v] -> Xb[(b,t)][(i,v)] bf16.
// Block = (b, group of 4 t). Coalesced reads (400B rows) and writes (packed uint).
// ---------------------------------------------------------------------------
#define XTS 101   // padded LDS row stride (96 rows x 100 cols)
__global__ __launch_bounds__(256) void xprep_t(const float* __restrict__ x,
                                               unsigned int* __restrict__ Xb)
{
    __shared__ float tile[CIN*XTS];   // 38.8 KB
    const int tid = threadIdx.x;
    const int b  = blockIdx.x;
    const int t0 = blockIdx.y * 4;
    const float* xb = x + (size_t)b*CIN*TV + (size_t)t0*VV;
    for (int e = tid; e < CIN*100; e += 256) {
        int i = e / 100, q = e - i*100;
        tile[i*XTS + q] = xb[(size_t)i*TV + q];
    }
    __syncthreads();
    // write 4 rows of Xb, 2 bf16 (one uint) per unit
    for (int e2 = tid; e2 < 4*1200; e2 += 256) {
        int tl = e2 / 1200;
        int r  = e2 - tl*1200;
        int k0 = r*2, k1 = k0 + 1;
        int i0 = k0 / VV, v0 = k0 - i0*VV;
        int i1 = k1 / VV, v1 = k1 - i1*VV;
        float f0 = tile[i0*XTS + tl*VV + v0];
        float f1 = tile[i1*XTS + tl*VV + v1];
        unsigned int u = ((unsigned int)f2bf(f1) << 16) | (unsigned int)f2bf(f0);
        Xb[((size_t)(b*TT + t0 + tl) * MK >> 1) + r] = u;
    }
}

// ---------------------------------------------------------------------------
// GEMM: z = W2b[M=2432,K=2400] x Xb[N=9216,K=2400]^T + zbias, written directly
// into out[b][c][t][v] (raw pre-window z, fp32). 128x128 tile, BK=32, 4 waves,
// global_load_lds width-16 staging, 16x16x32 bf16 MFMA, XOR-swizzled LDS.
// ---------------------------------------------------------------------------
__global__ __launch_bounds__(256) void gemm_zb(
    const __hip_bfloat16* __restrict__ W2b,
    const __hip_bfloat16* __restrict__ Xb,
    const float* __restrict__ zbias,
    float* __restrict__ out)
{
    __shared__ __hip_bfloat16 As[128*32];   // 8 KB, row r at r*32, chunk pos p at p*8
    __shared__ __hip_bfloat16 Bs[128*32];   // 8 KB
    const int tid  = threadIdx.x;
    const int lane = tid & 63;
    const int wave = tid >> 6;
    const int m0 = blockIdx.x * 128;
    const int n0 = blockIdx.y * 128;
    const int m_off = (wave & 1) * 64;
    const int n_off = (wave >> 1) * 64;

    // staging: thread tid covers (row r0, pos p) and (row r0+64, pos p).
    // LDS pos p holds global chunk j = p ^ ((r>>1)&3)  (swizzle, same for r and r+64)
    const int r0 = tid >> 2;
    const int p  = tid & 3;
    const int j  = p ^ ((r0 >> 1) & 3);
    const __hip_bfloat16* gA0 = W2b + (size_t)(m0 + r0) * MK + j*8;
    const __hip_bfloat16* gA1 = gA0 + (size_t)64 * MK;
    const __hip_bfloat16* gB0 = Xb  + (size_t)(n0 + r0) * MK + j*8;
    const __hip_bfloat16* gB1 = gB0 + (size_t)64 * MK;
    __hip_bfloat16* lA0 = As + tid*8;
    __hip_bfloat16* lA1 = As + tid*8 + 2048;
    __hip_bfloat16* lB0 = Bs + tid*8;
    __hip_bfloat16* lB1 = Bs + tid*8 + 2048;

    f32x4 acc[4][4] = {};
    // fragment read offsets (loop-invariant): row m, chunk c=lane>>4 at
    // swizzled pos = c ^ ((m>>1)&3)
    int aoff[4], boff[4];
    const int c_chunk = lane >> 4;
    #pragma unroll
    for (int mt = 0; mt < 4; ++mt) {
        int m = m_off + mt*16 + (lane & 15);
        aoff[mt] = m*32 + (c_chunk ^ ((m >> 1) & 3)) * 8;
        int n = n_off + mt*16 + (lane & 15);
        boff[mt] = n*32 + (c_chunk ^ ((n >> 1) & 3)) * 8;
    }

    for (int k = 0; k < MK; k += 32) {
        gload_lds16(gA0, lA0);
        gload_lds16(gA1, lA1);
        gload_lds16(gB0, lB0);
        gload_lds16(gB1, lB1);
        gA0 += 32; gA1 += 32; gB0 += 32; gB1 += 32;
        __syncthreads();
        bf16x8 af[4], bfr[4];
        #pragma unroll
        for (int mt = 0; mt < 4; ++mt) af[mt]  = *(const bf16x8*)&As[aoff[mt]];
        #pragma unroll
        for (int nt = 0; nt < 4; ++nt) bfr[nt] = *(const bf16x8*)&Bs[boff[nt]];
        #pragma unroll
        for (int mt = 0; mt < 4; ++mt)
            #pragma unroll
            for (int nt = 0; nt < 4; ++nt)
                acc[mt][nt] = __builtin_amdgcn_mfma_f32_16x16x32_bf16(
                    af[mt], bfr[nt], acc[mt][nt], 0, 0, 0);
        __syncthreads();
    }

    // epilogue: C/D layout col=lane&15, row=(lane>>4)*4+r; scatter to [b][c][t][v]
    const int colb = n0 + n_off + (lane & 15);
    #pragma unroll
    for (int nt = 0; nt < 4; ++nt) {
        int col = colb + nt*16;
        int b = col / TT, t = col - b*TT;
        float* obase = out + ((size_t)b*COUT*TT + t) * VV;
        #pragma unroll
        for (int mt = 0; mt < 4; ++mt) {
            int rowb = m0 + m_off + mt*16 + (lane >> 4)*4;
            #pragma unroll
            for (int r = 0; r < 4; ++r) {
                int row = rowb + r;
                if (row < 2400) {
                    int c = row / VV, v = row - c*VV;
                    obase[(size_t)c*TV + v] = acc[mt][nt][r] + zbias[row];
                }
            }
        }
    }
}

// ---------------------------------------------------------------------------
// k2: stats only. Per (b,c) slab: stage z (fp32, in out buffer) in LDS,
// compute window-5 average on the fly, accumulate per-channel sum/sumsq.
// ---------------------------------------------------------------------------
__global__ __launch_bounds__(256) void k2_stats(
    const float* __restrict__ zbuf, float* __restrict__ ssum, float* __restrict__ ssq)
{
    __shared__ float zs[TV];    // 28.8 KB
    __shared__ float red[8];
    const int tid = threadIdx.x;
    const int b = blockIdx.x / COUT;
    const int c = blockIdx.x - b*COUT;
    const float4* slab4 = (const float4*)(zbuf + (size_t)(b*COUT + c) * TV);
    float4* zs4 = (float4*)zs;
    for (int e = tid; e < TV/4; e += 256) zs4[e] = slab4[e];
    __syncthreads();

    float ls = 0.f, ls2 = 0.f;
    for (int e = tid; e < TV; e += 256) {
        int t = e / VV;
        float acc = zs[e];
        if (t >= 1)    acc += zs[e - VV];
        if (t >= 2)    acc += zs[e - 2*VV];
        if (t <= TT-2) acc += zs[e + VV];
        if (t <= TT-3) acc += zs[e + 2*VV];
        acc *= (1.0f / WSZ);
        ls  += acc;
        ls2 += acc * acc;
    }
    #pragma unroll
    for (int off = 32; off > 0; off >>= 1) {
        ls  += __shfl_down(ls,  off, 64);
        ls2 += __shfl_down(ls2, off, 64);
    }
    int lane = tid & 63, wid = tid >> 6;
    if (lane == 0) { red[wid*2] = ls; red[wid*2+1] = ls2; }
    __syncthreads();
    if (tid == 0) {
        atomicAdd(&ssum[c], red[0] + red[2] + red[4] + red[6]);
        atomicAdd(&ssq[c],  red[1] + red[3] + red[5] + red[7]);
    }
}

__global__ void k3_finalize(const float* __restrict__ ssum, const float* __restrict__ ssq,
                            const float* __restrict__ gamma, const float* __restrict__ beta,
                            float* __restrict__ scale, float* __restrict__ bias)
{
    int c = threadIdx.x;
    if (c < COUT) {
        const float invN = 1.0f / (float)(BB * TV);
        float mean = ssum[c] * invN;
        float var  = ssq[c] * invN - mean * mean;
        float inv  = rsqrtf(var + BN_EPS);
        float sc   = gamma[c] * inv;
        scale[c] = sc;
        bias[c]  = beta[c] - mean * sc;
    }
}

// ---------------------------------------------------------------------------
// k4: per (b,c) slab, IN PLACE: stage z in LDS, window-5 + normalize + relu,
// write back float4. Slab-local, so in-place is race-free.
// ---------------------------------------------------------------------------
__global__ __launch_bounds__(256) void k4_win_norm(
    float* __restrict__ buf, const float* __restrict__ scale, const float* __restrict__ bias)
{
    __shared__ float zs[TV];    // 28.8 KB
    const int tid = threadIdx.x;
    const int b = blockIdx.x / COUT;
    const int c = blockIdx.x - b*COUT;
    float* slab = buf + (size_t)(b*COUT + c) * TV;
    float4* slab4 = (float4*)slab;
    float4* zs4 = (float4*)zs;
    for (int e = tid; e < TV/4; e += 256) zs4[e] = slab4[e];
    __syncthreads();

    const float sc = scale[c], bi = bias[c];
    for (int u = tid; u < TV/4; u += 256) {
        float4 o;
        #pragma unroll
        for (int jj = 0; jj < 4; ++jj) {
            int e = u*4 + jj;
            int t = e / VV;
            float acc = zs[e];
            if (t >= 1)    acc += zs[e - VV];
            if (t >= 2)    acc += zs[e - 2*VV];
            if (t <= TT-2) acc += zs[e + VV];
            if (t <= TT-3) acc += zs[e + 2*VV];
            float val = fmaxf(fmaf(acc * (1.0f / WSZ), sc, bi), 0.0f);
            ((float*)&o)[jj] = val;
        }
        slab4[u] = o;
    }
}

extern "C" void kernel_launch(void* const* d_in, const int* in_sizes, int n_in,
                              void* d_out, int out_size, void* d_ws, size_t ws_size,
                              hipStream_t stream) {
    const float* x      = (const float*)d_in[0];
    const float* A      = (const float*)d_in[1];
    const float* conv_w = (const float*)d_in[2];
    const float* conv_b = (const float*)d_in[3];
    const float* gamma  = (const float*)d_in[4];
    const float* beta   = (const float*)d_in[5];
    float* out = (float*)d_out;

    // ws layout: zbias(2400 f) | ssum(96) | ssq(96) | scale(96) | bias(96) | Xb bf16 | W2b bf16
    float* zbias = (float*)d_ws;
    float* ssum  = zbias + 2400;
    float* ssq   = ssum + COUT;
    float* scale = ssq  + COUT;
    float* bias  = scale + COUT;
    __hip_bfloat16* Xb  = (__hip_bfloat16*)(bias + COUT);
    __hip_bfloat16* W2b = Xb + (size_t)GN * MK;
    // total: ~9.6 KB + 44.24 MB + 11.67 MB = 55.9 MB

    wprep  <<<dim3(GMP),             dim3(256), 0, stream>>>(conv_w, A, conv_b, W2b, zbias, ssum);
    xprep_t<<<dim3(BB, TT/4),        dim3(256), 0, stream>>>(x, (unsigned int*)Xb);
    gemm_zb<<<dim3(GMP/128, GN/128), dim3(256), 0, stream>>>(W2b, Xb, zbias, out);
    k2_stats<<<dim3(BB*COUT),        dim3(256), 0, stream>>>(out, ssum, ssq);
    k3_finalize<<<dim3(1),           dim3(128), 0, stream>>>(ssum, ssq, gamma, beta, scale, bias);
    k4_win_norm<<<dim3(BB*COUT),     dim3(256), 0, stream>>>(out, scale, bias);
}

// Round 5
// 303.614 us; speedup vs baseline: 1.4967x; 1.4967x over previous
//
#include <hip/hip_runtime.h>
#include <hip/hip_bf16.h>

// Problem constants
#define BB 32
#define CIN 96
#define TT 288
#define VV 25
#define SS 3
#define COUT 96
#define WSZ 5
#define BN_EPS 1e-5f
#define TV (TT*VV)              // 7200
#define KK 288                  // fused GEMM K = s*96+i
#define XCOLS 64                // XAtile rows allocated (50 used; 64 so junk reads stay in-bounds)

typedef __attribute__((ext_vector_type(8))) short bf16x8;
typedef __attribute__((ext_vector_type(4))) float f32x4;

__device__ __forceinline__ unsigned short f2bf(float f) {
    unsigned u = __float_as_uint(f);
    return (unsigned short)((u + 0x7fffu + ((u >> 16) & 1u)) >> 16);  // RNE
}

// ---------------------------------------------------------------------------
// prep: Wflat[c][k=s*96+i] = bf16(conv_w[(s*96+c)*96+i]);
//       Bfr[f=s*2+nt][lane][j] = B-fragment of A_s for 16x16x32 MFMA
//          (k=n=(lane>>4)*8+j, col=m=nt*16+(lane&15); zero outside 25x25);
//       zbias[c*25+m] = sum_s cb[s*96+c] * sum_n A[s,n,m];
//       stats[0..191] = 0.
// ---------------------------------------------------------------------------
__global__ __launch_bounds__(256) void prep(
    const float* __restrict__ conv_w, const float* __restrict__ A,
    const float* __restrict__ cb,
    __hip_bfloat16* __restrict__ Wflat,   // [96][288]
    __hip_bfloat16* __restrict__ Bfr,     // [6][64][8]
    float* __restrict__ zbias,            // [2400]
    float* __restrict__ stats)            // [192]
{
    int id = blockIdx.x*256 + threadIdx.x;
    if (id < 27648) {
        int c = id / KK, k = id - c*KK;
        int s = k / CIN, i = k - s*CIN;
        Wflat[id] = __float2bfloat16(conv_w[(s*COUT + c)*CIN + i]);
    } else if (id < 27648 + 3072) {
        int e = id - 27648;               // f*512 + l*8 + j
        int f = e >> 9, rem = e & 511;
        int l = rem >> 3, j = rem & 7;
        int s = f >> 1, nt = f & 1;
        int n = (l >> 4)*8 + j;
        int m = nt*16 + (l & 15);
        float v = (n < VV && m < VV) ? A[(s*VV + n)*VV + m] : 0.0f;
        Bfr[e] = __float2bfloat16(v);
    } else if (id < 27648 + 3072 + 2400) {
        int e = id - 27648 - 3072;
        int c = e / VV, m = e - c*VV;
        float v = 0.f;
        #pragma unroll
        for (int s = 0; s < SS; ++s) {
            float sa = 0.f;
            #pragma unroll
            for (int n = 0; n < VV; ++n) sa += A[(s*VV + n)*VV + m];
            v = fmaf(cb[s*COUT + c], sa, v);
        }
        zbias[e] = v;
    } else if (id < 27648 + 3072 + 2400 + 192) {
        stats[id - 27648 - 3072 - 2400] = 0.0f;
    }
}

// ---------------------------------------------------------------------------
// fused: per (b, t-tile of 2):
//  phase 1: XAt[col=(tl,m)][k=(s,i)] = sum_n x[b,i,t0+tl,n] * A[s,n,m]
//           via MFMA (M=(i,tl)=192 rows, N=m, K=n); scatter bf16 to LDS
//           with R4's XOR chunk swizzle (conflict-free b128 reads later).
//  phase 2: z[c][col] = sum_k Wflat[c][k] * XAt[col][k]  (barrier-free
//           9-iter K-loop; A-frags from global/L2, B-frags from LDS),
//           + zbias, written directly to out[b][c][t][m].
// ---------------------------------------------------------------------------
__global__ __launch_bounds__(256) void fused(
    const float* __restrict__ x,
    const __hip_bfloat16* __restrict__ Wflat,
    const __hip_bfloat16* __restrict__ Bfr,
    const float* __restrict__ zbias,
    float* __restrict__ out)
{
    __shared__ __hip_bfloat16 XAt[XCOLS*KK];  // 36,864 B
    const int tid  = threadIdx.x;
    const int lane = tid & 63;
    const int wave = tid >> 6;
    const int quad = lane >> 4;       // 0..3
    const int lrow = lane & 15;
    const int tile = blockIdx.x;      // 0..143
    const int b    = blockIdx.y;      // 0..31
    const int t0   = tile*2;

    // 6 B1 fragments (A_s matrices), precomputed per-lane by prep
    bf16x8 bf1[6];
    #pragma unroll
    for (int f = 0; f < 6; ++f)
        bf1[f] = *(const bf16x8*)(Bfr + (f*64 + lane)*8);

    // ---- phase 1: wave w handles M-tiles 3w..3w+2 (rows = i*2+tl)
    #pragma unroll
    for (int mt3 = 0; mt3 < 3; ++mt3) {
        const int Mtile = wave*3 + mt3;
        // A1 frag: this lane supplies row = Mtile*16 + lrow, k(=n) = quad*8+j
        const int arow = Mtile*16 + lrow;
        const int ai = arow >> 1, atl = arow & 1;
        const float* xrow = x + ((size_t)(b*CIN + ai)*TT + (t0 + atl))*VV;
        float xv[8];
        if (quad < 3) {
            #pragma unroll
            for (int j = 0; j < 8; ++j) xv[j] = xrow[quad*8 + j];
        } else {
            #pragma unroll
            for (int j = 0; j < 8; ++j) xv[j] = 0.f;
            xv[0] = xrow[24];   // n=24 valid; k=25..31 hit zero B entries
        }
        bf16x8 af;
        #pragma unroll
        for (int j = 0; j < 8; ++j) ((short*)&af)[j] = (short)f2bf(xv[j]);

        // D rows owned by this lane: row16 = quad*4 + r ; i0 = Mtile*8+quad*2
        const int i0 = Mtile*8 + quad*2;
        #pragma unroll
        for (int s = 0; s < SS; ++s) {
            #pragma unroll
            for (int nt = 0; nt < 2; ++nt) {
                f32x4 d = {0.f, 0.f, 0.f, 0.f};
                d = __builtin_amdgcn_mfma_f32_16x16x32_bf16(af, bf1[s*2+nt], d, 0, 0, 0);
                const int m = nt*16 + lrow;
                if (m < VV) {
                    const int k0 = s*CIN + i0;         // even
                    const int g  = k0 >> 3, o = k0 & 7;
                    #pragma unroll
                    for (int tl = 0; tl < 2; ++tl) {   // pair (d[tl], d[tl+2]) -> (i0, i0+1)
                        const int col = tl*VV + m;
                        const int gs  = (g & ~3) | ((g & 3) ^ ((col >> 1) & 3));
                        unsigned int pv = (unsigned int)f2bf(d[tl])
                                        | ((unsigned int)f2bf(d[tl+2]) << 16);
                        ((unsigned int*)XAt)[(col*KK + gs*8 + o) >> 1] = pv;
                    }
                }
            }
        }
    }
    __syncthreads();

    // ---- phase 2: wave split 2x2: mh -> c-tiles, nh -> col-tiles
    const int mh = wave & 1, nh = wave >> 1;
    f32x4 acc[3][2] = {};
    for (int it = 0; it < 9; ++it) {
        const int k0 = it*32;
        bf16x8 bfrag[2];
        #pragma unroll
        for (int ct = 0; ct < 2; ++ct) {
            const int cl = (nh*2 + ct)*16 + lrow;           // col (junk >=50 ok)
            const int g0 = it*4 + (quad ^ ((cl >> 1) & 3));
            bfrag[ct] = *(const bf16x8*)&XAt[cl*KK + g0*8];
        }
        #pragma unroll
        for (int mt = 0; mt < 3; ++mt) {
            const int c = (mh*3 + mt)*16 + lrow;
            bf16x8 afrag = *(const bf16x8*)(Wflat + c*KK + k0 + quad*8);
            #pragma unroll
            for (int ct = 0; ct < 2; ++ct)
                acc[mt][ct] = __builtin_amdgcn_mfma_f32_16x16x32_bf16(
                    afrag, bfrag[ct], acc[mt][ct], 0, 0, 0);
        }
    }

    // ---- epilogue: D col = lane&15, row = quad*4+r ; scatter + zbias
    #pragma unroll
    for (int ct = 0; ct < 2; ++ct) {
        const int cl = (nh*2 + ct)*16 + lrow;
        if (cl < 2*VV) {
            const int tl = (cl >= VV) ? 1 : 0;
            const int m  = cl - tl*VV;
            float* obase = out + ((size_t)b*COUT*TT + (t0 + tl))*VV + m;
            #pragma unroll
            for (int mt = 0; mt < 3; ++mt) {
                const int cbase = (mh*3 + mt)*16 + quad*4;
                #pragma unroll
                for (int r = 0; r < 4; ++r) {
                    const int c = cbase + r;
                    obase[(size_t)c*TV] = acc[mt][ct][r] + zbias[c*VV + m];
                }
            }
        }
    }
}

// ---------------------------------------------------------------------------
// k2: stats only. Per (b,c) slab: stage z in LDS, window-5 on the fly,
// accumulate per-channel sum/sumsq.
// ---------------------------------------------------------------------------
__global__ __launch_bounds__(256) void k2_stats(
    const float* __restrict__ zbuf, float* __restrict__ ssum, float* __restrict__ ssq)
{
    __shared__ float zs[TV];    // 28.8 KB
    __shared__ float red[8];
    const int tid = threadIdx.x;
    const int b = blockIdx.x / COUT;
    const int c = blockIdx.x - b*COUT;
    const float4* slab4 = (const float4*)(zbuf + (size_t)(b*COUT + c) * TV);
    float4* zs4 = (float4*)zs;
    for (int e = tid; e < TV/4; e += 256) zs4[e] = slab4[e];
    __syncthreads();

    float ls = 0.f, ls2 = 0.f;
    for (int e = tid; e < TV; e += 256) {
        int t = e / VV;
        float acc = zs[e];
        if (t >= 1)    acc += zs[e - VV];
        if (t >= 2)    acc += zs[e - 2*VV];
        if (t <= TT-2) acc += zs[e + VV];
        if (t <= TT-3) acc += zs[e + 2*VV];
        acc *= (1.0f / WSZ);
        ls  += acc;
        ls2 += acc * acc;
    }
    #pragma unroll
    for (int off = 32; off > 0; off >>= 1) {
        ls  += __shfl_down(ls,  off, 64);
        ls2 += __shfl_down(ls2, off, 64);
    }
    int lane = tid & 63, wid = tid >> 6;
    if (lane == 0) { red[wid*2] = ls; red[wid*2+1] = ls2; }
    __syncthreads();
    if (tid == 0) {
        atomicAdd(&ssum[c], red[0] + red[2] + red[4] + red[6]);
        atomicAdd(&ssq[c],  red[1] + red[3] + red[5] + red[7]);
    }
}

__global__ void k3_finalize(const float* __restrict__ ssum, const float* __restrict__ ssq,
                            const float* __restrict__ gamma, const float* __restrict__ beta,
                            float* __restrict__ scale, float* __restrict__ bias)
{
    int c = threadIdx.x;
    if (c < COUT) {
        const float invN = 1.0f / (float)(BB * TV);
        float mean = ssum[c] * invN;
        float var  = ssq[c] * invN - mean * mean;
        float inv  = rsqrtf(var + BN_EPS);
        float sc   = gamma[c] * inv;
        scale[c] = sc;
        bias[c]  = beta[c] - mean * sc;
    }
}

// ---------------------------------------------------------------------------
// k4: per (b,c) slab, IN PLACE: window-5 + normalize + relu.
// ---------------------------------------------------------------------------
__global__ __launch_bounds__(256) void k4_win_norm(
    float* __restrict__ buf, const float* __restrict__ scale, const float* __restrict__ bias)
{
    __shared__ float zs[TV];    // 28.8 KB
    const int tid = threadIdx.x;
    const int b = blockIdx.x / COUT;
    const int c = blockIdx.x - b*COUT;
    float* slab = buf + (size_t)(b*COUT + c) * TV;
    float4* slab4 = (float4*)slab;
    float4* zs4 = (float4*)zs;
    for (int e = tid; e < TV/4; e += 256) zs4[e] = slab4[e];
    __syncthreads();

    const float sc = scale[c], bi = bias[c];
    for (int u = tid; u < TV/4; u += 256) {
        float4 o;
        #pragma unroll
        for (int jj = 0; jj < 4; ++jj) {
            int e = u*4 + jj;
            int t = e / VV;
            float acc = zs[e];
            if (t >= 1)    acc += zs[e - VV];
            if (t >= 2)    acc += zs[e - 2*VV];
            if (t <= TT-2) acc += zs[e + VV];
            if (t <= TT-3) acc += zs[e + 2*VV];
            float val = fmaxf(fmaf(acc * (1.0f / WSZ), sc, bi), 0.0f);
            ((float*)&o)[jj] = val;
        }
        slab4[u] = o;
    }
}

extern "C" void kernel_launch(void* const* d_in, const int* in_sizes, int n_in,
                              void* d_out, int out_size, void* d_ws, size_t ws_size,
                              hipStream_t stream) {
    const float* x      = (const float*)d_in[0];
    const float* A      = (const float*)d_in[1];
    const float* conv_w = (const float*)d_in[2];
    const float* conv_b = (const float*)d_in[3];
    const float* gamma  = (const float*)d_in[4];
    const float* beta   = (const float*)d_in[5];
    float* out = (float*)d_out;

    // ws layout (tiny now): zbias(2400 f) | ssum(96) | ssq(96) | scale(96) | bias(96)
    //                       | Wflat (27648 bf16) | Bfr (3072 bf16)
    float* zbias = (float*)d_ws;
    float* ssum  = zbias + 2400;
    float* ssq   = ssum + COUT;
    float* scale = ssq  + COUT;
    float* bias  = scale + COUT;
    __hip_bfloat16* Wflat = (__hip_bfloat16*)(bias + COUT);
    __hip_bfloat16* Bfr   = Wflat + (size_t)COUT * KK;

    prep <<<dim3(131),        dim3(256), 0, stream>>>(conv_w, A, conv_b, Wflat, Bfr, zbias, ssum);
    fused<<<dim3(TT/2, BB),   dim3(256), 0, stream>>>(x, Wflat, Bfr, zbias, out);
    k2_stats<<<dim3(BB*COUT), dim3(256), 0, stream>>>(out, ssum, ssq);
    k3_finalize<<<dim3(1),    dim3(128), 0, stream>>>(ssum, ssq, gamma, beta, scale, bias);
    k4_win_norm<<<dim3(BB*COUT), dim3(256), 0, stream>>>(out, scale, bias);
}